// Round 2
// baseline (1672.006 us; speedup 1.0000x reference)
//
#include <hip/hip_runtime.h>

#define HID 64

typedef float v2f __attribute__((ext_vector_type(2)));

// ---------------------------------------------------------------------------
// Lanes = nodes. Each wave owns 3 clusters = 60 nodes (lanes 0..59).
// Activations: per-wave LDS rows, stride 65 (conflict-free).
// Weights: staged per-matmul into block-shared LDS (wbuf); inner loop reads
// them as wave-uniform broadcasts (ds_read_b128, conflict-free) and issues
// packed v_pk_fma_f32 via float2 vectors.
// ---------------------------------------------------------------------------

__device__ __forceinline__ void stage4(float* dst, const float* __restrict__ src,
                                       int n4, int tid) {
  const float4* s = (const float4*)src;
  float4* d = (float4*)dst;
  for (int i = tid; i < n4; i += 256) d[i] = s[i];
}

// acc[F] = b + Arow[0..K) @ W[K][F]   (W, b are LDS or uniform global ptrs)
template <int KDIM, int FDIM>
__device__ __forceinline__ void matvec_w(const float* Arow,
                                         const float* W,
                                         const float* b,
                                         float* accf) {
  v2f* acc = (v2f*)accf;
  const v2f* bv = (const v2f*)b;
#pragma unroll
  for (int f = 0; f < FDIM / 2; ++f) acc[f] = bv[f];
#pragma unroll 4
  for (int k = 0; k < KDIM; ++k) {
    const float a = Arow[k];              // per-lane LDS read (stride-65 rows)
    v2f av = {a, a};
    const v2f* Wr = (const v2f*)(W + k * FDIM);
#pragma unroll
    for (int f = 0; f < FDIM / 2; ++f)
      acc[f] = __builtin_elementwise_fma(av, Wr[f], acc[f]);   // v_pk_fma_f32
  }
}

__device__ __forceinline__ void ln_relu_store(float* Arow, float* acc,
                                              const float* g, const float* be) {
  float mu = 0.f;
#pragma unroll
  for (int f = 0; f < HID; ++f) mu += acc[f];
  mu *= (1.0f / HID);
  float vs = 0.f;
#pragma unroll
  for (int f = 0; f < HID; ++f) { float d = acc[f] - mu; vs = fmaf(d, d, vs); }
  vs *= (1.0f / HID);
  const float rs = rsqrtf(vs + 1e-5f);
#pragma unroll
  for (int f = 0; f < HID; ++f) {
    float h = (acc[f] - mu) * rs * g[f] + be[f];
    Arow[f] = fmaxf(h, 0.f);
  }
}

// One subgraph layer. wbuf layout: w1 @0 (4096), b1 @4096, g @4160, be @4224;
// then (second stage) w2 @0 (2048), b2 @2048.
__device__ __forceinline__ void layer(float* A, float* Pw, float* wbuf, int tid,
                                      int rowoff, bool active, int lane, int mycl,
                                      int waveCluster, int C, bool last,
                                      const float* __restrict__ w1,
                                      const float* __restrict__ b1,
                                      const float* __restrict__ g,
                                      const float* __restrict__ be,
                                      const float* __restrict__ w2,
                                      const float* __restrict__ b2,
                                      float* __restrict__ ws) {
  __syncthreads();                       // everyone done with previous wbuf
  stage4(wbuf, w1, 1024, tid);
  stage4(wbuf + 4096, b1, 16, tid);
  stage4(wbuf + 4160, g, 16, tid);
  stage4(wbuf + 4224, be, 16, tid);
  __syncthreads();
  if (active) {
    float acc[HID];
    matvec_w<HID, HID>(A + rowoff, wbuf, wbuf + 4096, acc);
    ln_relu_store(A + rowoff, acc, wbuf + 4160, wbuf + 4224);
  }
  __syncthreads();                       // mm1 done reading w1
  stage4(wbuf, w2, 512, tid);
  stage4(wbuf + 2048, b2, 8, tid);
  __syncthreads();
  if (active) {
    float h2[32];
    matvec_w<HID, 32>(A + rowoff, wbuf, wbuf + 2048, h2);
#pragma unroll
    for (int j = 0; j < 32; ++j) A[rowoff + j] = h2[j];
  }
  __syncthreads();                       // h in LDS visible for pooling
  const int cl = lane >> 5, j = lane & 31;
  if (!last) {
    if (waveCluster + cl < C) {
      float m = -3.4e38f;
#pragma unroll
      for (int r = 0; r < 20; ++r) m = fmaxf(m, A[(cl * 20 + r) * 65 + j]);
      Pw[cl * 36 + j] = m;
    }
    if (lane < 32 && (waveCluster + 2 < C)) {
      float m = -3.4e38f;
#pragma unroll
      for (int r = 0; r < 20; ++r) m = fmaxf(m, A[(40 + r) * 65 + lane]);
      Pw[72 + lane] = m;
    }
    __syncthreads();
    if (active) {
#pragma unroll
      for (int q = 0; q < 32; ++q) A[rowoff + 32 + q] = Pw[mycl * 36 + q];
    }
  } else {
    // segmax(concat[h, pooled]) == [pooled, pooled] -> write ws directly
    if (waveCluster + cl < C) {
      float m = -3.4e38f;
#pragma unroll
      for (int r = 0; r < 20; ++r) m = fmaxf(m, A[(cl * 20 + r) * 65 + j]);
      const long gc = waveCluster + cl;
      ws[gc * 64 + j] = m;
      ws[gc * 64 + 32 + j] = m;
    }
    if (lane < 32 && (waveCluster + 2 < C)) {
      float m = -3.4e38f;
#pragma unroll
      for (int r = 0; r < 20; ++r) m = fmaxf(m, A[(40 + r) * 65 + lane]);
      const long gc = waveCluster + 2;
      ws[gc * 64 + lane] = m;
      ws[gc * 64 + 32 + lane] = m;
    }
  }
}

__global__ void __launch_bounds__(256, 2)
kA(const float* __restrict__ x,
   const float* __restrict__ pw1, const float* __restrict__ pb1,
   const float* __restrict__ pg,  const float* __restrict__ pbe,
   const float* __restrict__ pw2, const float* __restrict__ pb2,
   const float* __restrict__ w1a, const float* __restrict__ b1a,
   const float* __restrict__ ga,  const float* __restrict__ bea,
   const float* __restrict__ w2a, const float* __restrict__ b2a,
   const float* __restrict__ w1b, const float* __restrict__ b1b,
   const float* __restrict__ gb,  const float* __restrict__ beb,
   const float* __restrict__ w2b, const float* __restrict__ b2b,
   const float* __restrict__ w1c, const float* __restrict__ b1c,
   const float* __restrict__ gc,  const float* __restrict__ bec,
   const float* __restrict__ w2c, const float* __restrict__ b2c,
   float* __restrict__ ws, int C) {
  __shared__ float act[4][60 * 65];
  __shared__ float wbuf[4288];
  __shared__ float P[4][108];
  const int tid = threadIdx.x;
  const int lane = tid & 63;
  const int w = tid >> 6;
  const int waveCluster = blockIdx.x * 12 + w * 3;
  float* A = act[w];
  float* Pw = P[w];
  const int mycl = lane / 20;
  const bool active = (lane < 60) && (waveCluster + mycl < C);
  const int rowoff = lane * 65;

  if (active) {
    const int node = waveCluster * 20 + lane;
    const float4* xr = (const float4*)(x + (long)node * 16);
    float4 v0 = xr[0], v1 = xr[1], v2 = xr[2], v3 = xr[3];
    A[rowoff + 0]  = v0.x; A[rowoff + 1]  = v0.y; A[rowoff + 2]  = v0.z; A[rowoff + 3]  = v0.w;
    A[rowoff + 4]  = v1.x; A[rowoff + 5]  = v1.y; A[rowoff + 6]  = v1.z; A[rowoff + 7]  = v1.w;
    A[rowoff + 8]  = v2.x; A[rowoff + 9]  = v2.y; A[rowoff + 10] = v2.z; A[rowoff + 11] = v2.w;
    A[rowoff + 12] = v3.x; A[rowoff + 13] = v3.y; A[rowoff + 14] = v3.z; A[rowoff + 15] = v3.w;
  }
  // pre-MLP stage 1: 16 -> 64, LN, relu
  stage4(wbuf, pw1, 256, tid);
  stage4(wbuf + 1024, pb1, 16, tid);
  stage4(wbuf + 1088, pg, 16, tid);
  stage4(wbuf + 1152, pbe, 16, tid);
  __syncthreads();
  if (active) {
    float acc[HID];
    matvec_w<16, HID>(A + rowoff, wbuf, wbuf + 1024, acc);
    ln_relu_store(A + rowoff, acc, wbuf + 1088, wbuf + 1152);
  }
  __syncthreads();
  // pre-MLP stage 2: 64 -> 64
  stage4(wbuf, pw2, 1024, tid);
  stage4(wbuf + 4096, pb2, 16, tid);
  __syncthreads();
  if (active) {
    float acc[HID];
    matvec_w<HID, HID>(A + rowoff, wbuf, wbuf + 4096, acc);
#pragma unroll
    for (int f = 0; f < HID; ++f) A[rowoff + f] = acc[f];
  }

  layer(A, Pw, wbuf, tid, rowoff, active, lane, mycl, waveCluster, C, false,
        w1a, b1a, ga, bea, w2a, b2a, ws);
  layer(A, Pw, wbuf, tid, rowoff, active, lane, mycl, waveCluster, C, false,
        w1b, b1b, gb, beb, w2b, b2b, ws);
  layer(A, Pw, wbuf, tid, rowoff, active, lane, mycl, waveCluster, C, true,
        w1c, b1c, gc, bec, w2c, b2c, ws);
}

// Output MLP over C cluster rows: 64 -> 64 (LN, relu) -> 128, L2-normalize.
// Also writes batch_out (as float) at d_out + C*128.
__global__ void __launch_bounds__(128, 2)
kB(const float* __restrict__ ws, const int* __restrict__ batch,
   const float* __restrict__ ow1, const float* __restrict__ ob1,
   const float* __restrict__ og,  const float* __restrict__ obe,
   const float* __restrict__ ow2, const float* __restrict__ ob2,
   float* __restrict__ out, int C) {
  __shared__ float buf[2][64 * 65];
  const int lane = threadIdx.x & 63;
  const int w = threadIdx.x >> 6;
  float* Brow = buf[w] + lane * 65;
  const long r = (long)(blockIdx.x * 2 + w) * 64 + lane;
  if (r < C) {
    const float4* src = (const float4*)(ws + r * 64);
#pragma unroll
    for (int q = 0; q < 16; ++q) {
      float4 v = src[q];
      Brow[q * 4 + 0] = v.x; Brow[q * 4 + 1] = v.y;
      Brow[q * 4 + 2] = v.z; Brow[q * 4 + 3] = v.w;
    }
    float acc[HID];
    matvec_w<HID, HID>(Brow, ow1, ob1, acc);
    ln_relu_store(Brow, acc, og, obe);
    float o[128];
    matvec_w<HID, 128>(Brow, ow2, ob2, o);
    float n2 = 0.f;
#pragma unroll
    for (int f = 0; f < 128; ++f) n2 = fmaf(o[f], o[f], n2);
    const float s = 1.0f / fmaxf(sqrtf(n2), 1e-12f);
    float4* dst = (float4*)(out + r * 128);
#pragma unroll
    for (int q = 0; q < 32; ++q) {
      float4 v = { o[q * 4] * s, o[q * 4 + 1] * s, o[q * 4 + 2] * s, o[q * 4 + 3] * s };
      dst[q] = v;
    }
    out[(long)C * 128 + r] = (float)batch[r * 20];
  }
}

extern "C" void kernel_launch(void* const* d_in, const int* in_sizes, int n_in,
                              void* d_out, int out_size, void* d_ws, size_t ws_size,
                              hipStream_t stream) {
  const float* x     = (const float*)d_in[0];
  const int*   batch = (const int*)d_in[2];
  const float* pw1 = (const float*)d_in[3];
  const float* pb1 = (const float*)d_in[4];
  const float* pg  = (const float*)d_in[5];
  const float* pbe = (const float*)d_in[6];
  const float* pw2 = (const float*)d_in[7];
  const float* pb2 = (const float*)d_in[8];
  const float* w1a = (const float*)d_in[9];
  const float* b1a = (const float*)d_in[10];
  const float* ga  = (const float*)d_in[11];
  const float* bea = (const float*)d_in[12];
  const float* w2a = (const float*)d_in[13];
  const float* b2a = (const float*)d_in[14];
  const float* w1b = (const float*)d_in[15];
  const float* b1b = (const float*)d_in[16];
  const float* gb  = (const float*)d_in[17];
  const float* beb = (const float*)d_in[18];
  const float* w2b = (const float*)d_in[19];
  const float* b2b = (const float*)d_in[20];
  const float* w1c = (const float*)d_in[21];
  const float* b1c = (const float*)d_in[22];
  const float* gc  = (const float*)d_in[23];
  const float* bec = (const float*)d_in[24];
  const float* w2c = (const float*)d_in[25];
  const float* b2c = (const float*)d_in[26];
  const float* ow1 = (const float*)d_in[27];
  const float* ob1 = (const float*)d_in[28];
  const float* og  = (const float*)d_in[29];
  const float* obe = (const float*)d_in[30];
  const float* ow2 = (const float*)d_in[31];
  const float* ob2 = (const float*)d_in[32];

  const int N = in_sizes[0] / 16;
  const int C = N / 20;
  float* ws  = (float*)d_ws;
  float* out = (float*)d_out;

  const int blocksA = (C + 11) / 12;   // 12 clusters per block (4 waves x 3)
  hipLaunchKernelGGL(kA, dim3(blocksA), dim3(256), 0, stream,
                     x, pw1, pb1, pg, pbe, pw2, pb2,
                     w1a, b1a, ga, bea, w2a, b2a,
                     w1b, b1b, gb, beb, w2b, b2b,
                     w1c, b1c, gc, bec, w2c, b2c,
                     ws, C);

  const int blocksB = (C + 127) / 128; // 128 rows per block (2 waves x 64)
  hipLaunchKernelGGL(kB, dim3(blocksB), dim3(128), 0, stream,
                     ws, batch, ow1, ob1, og, obe, ow2, ob2, out, C);
}

// Round 3
// 775.927 us; speedup vs baseline: 2.1548x; 2.1548x over previous
//
#include <hip/hip_runtime.h>

// ---------------------------------------------------------------------------
// MFMA (16x16x32 bf16) implementation with hi/lo split for fp32-level accuracy.
// Block = 320 threads (5 waves) handles 160 nodes = 8 clusters.
// Each wave owns 2 M-tiles of 16 nodes. Activations: block LDS [160][76] fp32.
// Weights: staged per-layer, transposed, as bf16 hi/lo [F][72] (short).
// D = Ahi*Whi + Ahi*Wlo + Alo*Whi  (3 MFMAs per tile-step).
// Fragment maps (m89/m91-verified): A: m=lane&15, k=(lane>>4)*8+j;
// C/D: col=lane&15, row=(lane>>4)*4+reg. B assumed symmetric: n=lane&15.
// ---------------------------------------------------------------------------

#define STR  76   // act row stride (floats): 76%32=12 -> <=2-way banks, 16B aligned
#define WSTR 72   // weight row stride (shorts): 144B, 16B aligned

typedef short v8s __attribute__((ext_vector_type(8)));
typedef float v4f __attribute__((ext_vector_type(4)));

#define MFMA __builtin_amdgcn_mfma_f32_16x16x32_bf16

__device__ __forceinline__ void split8(const float* p, v8s& hi, v8s& lo) {
  float4 u = *(const float4*)p;
  float4 v = *(const float4*)(p + 4);
  float vals[8] = {u.x, u.y, u.z, u.w, v.x, v.y, v.z, v.w};
#pragma unroll
  for (int e = 0; e < 8; ++e) {
    __bf16 hb = (__bf16)vals[e];
    float hf = (float)hb;
    __bf16 lb = (__bf16)(vals[e] - hf);
    hi[e] = __builtin_bit_cast(short, hb);
    lo[e] = __builtin_bit_cast(short, lb);
  }
}

// Stage W[K][F] fp32 (global) -> transposed bf16 hi/lo LDS arrays [F][WSTR].
__device__ __forceinline__ void stageW(const float* __restrict__ W,
                                       short* whi, short* wlo,
                                       int K, int F, int tid, int nthr) {
  const float4* W4 = (const float4*)W;
  const int total = (K * F) >> 2;
  const int fq = F >> 2;
  for (int i = tid; i < total; i += nthr) {
    float4 v = W4[i];
    int k = i / fq;
    int f0 = (i - k * fq) << 2;
    float vals[4] = {v.x, v.y, v.z, v.w};
#pragma unroll
    for (int e = 0; e < 4; ++e) {
      float x = vals[e];
      __bf16 hb = (__bf16)x;
      float hf = (float)hb;
      __bf16 lb = (__bf16)(x - hf);
      whi[(f0 + e) * WSTR + k] = __builtin_bit_cast(short, hb);
      wlo[(f0 + e) * WSTR + k] = __builtin_bit_cast(short, lb);
    }
  }
}

__device__ __forceinline__ void stageVec(const float* __restrict__ src,
                                         float* dst, int n, int tid, int nthr) {
  for (int i = tid; i < n; i += nthr) dst[i] = src[i];
}

// One M-tile matmul: acc[NT] over K = KS*32, A from act LDS, W from staged LDS.
template <int NT, int KS>
__device__ __forceinline__ void mm_frag(const float* actb, int mtbase,
                                        const short* whi, const short* wlo,
                                        const float* bias, int col, int quad,
                                        v4f* acc) {
#pragma unroll
  for (int t = 0; t < NT; ++t) {
    float bv = bias[t * 16 + col];
    acc[t] = (v4f){bv, bv, bv, bv};
  }
#pragma unroll
  for (int ks = 0; ks < KS; ++ks) {
    v8s ah, al;
    split8(actb + (mtbase + col) * STR + ks * 32 + quad * 8, ah, al);
#pragma unroll
    for (int t = 0; t < NT; ++t) {
      const v8s bh = *(const v8s*)(whi + (t * 16 + col) * WSTR + ks * 32 + quad * 8);
      const v8s bl = *(const v8s*)(wlo + (t * 16 + col) * WSTR + ks * 32 + quad * 8);
      acc[t] = MFMA(al, bh, acc[t], 0, 0, 0);
      acc[t] = MFMA(ah, bl, acc[t], 0, 0, 0);
      acc[t] = MFMA(ah, bh, acc[t], 0, 0, 0);
    }
  }
}

// LayerNorm(64) + ReLU on 4 C-frags, write to act rows cols 0..63.
__device__ __forceinline__ void ln_relu_write(float* actb, int mtbase, int col,
                                              int quad, v4f* acc,
                                              const float* g, const float* be) {
  float mu[4], sq[4];
#pragma unroll
  for (int r = 0; r < 4; ++r) {
    mu[r] = acc[0][r] + acc[1][r] + acc[2][r] + acc[3][r];
    sq[r] = fmaf(acc[0][r], acc[0][r], fmaf(acc[1][r], acc[1][r],
            fmaf(acc[2][r], acc[2][r], acc[3][r] * acc[3][r])));
  }
#pragma unroll
  for (int m = 1; m <= 8; m <<= 1) {
#pragma unroll
    for (int r = 0; r < 4; ++r) {
      mu[r] += __shfl_xor(mu[r], m);
      sq[r] += __shfl_xor(sq[r], m);
    }
  }
  float rs[4];
#pragma unroll
  for (int r = 0; r < 4; ++r) {
    float m_ = mu[r] * (1.0f / 64.0f);
    float v_ = sq[r] * (1.0f / 64.0f) - m_ * m_;
    mu[r] = m_;
    rs[r] = rsqrtf(v_ + 1e-5f);
  }
#pragma unroll
  for (int t = 0; t < 4; ++t) {
    float gv = g[t * 16 + col], bv = be[t * 16 + col];
#pragma unroll
    for (int r = 0; r < 4; ++r) {
      float val = (acc[t][r] - mu[r]) * rs[r] * gv + bv;
      actb[(mtbase + quad * 4 + r) * STR + t * 16 + col] = fmaxf(val, 0.f);
    }
  }
}

template <int NT>
__device__ __forceinline__ void plain_write(float* actb, int mtbase, int col,
                                            int quad, v4f* acc) {
#pragma unroll
  for (int t = 0; t < NT; ++t)
#pragma unroll
    for (int r = 0; r < 4; ++r)
      actb[(mtbase + quad * 4 + r) * STR + t * 16 + col] = acc[t][r];
}

__global__ void __launch_bounds__(320, 2)
kA(const float* __restrict__ x,
   const float* __restrict__ pw1, const float* __restrict__ pb1,
   const float* __restrict__ pg,  const float* __restrict__ pbe,
   const float* __restrict__ pw2, const float* __restrict__ pb2,
   const float* __restrict__ w1a, const float* __restrict__ b1a,
   const float* __restrict__ ga,  const float* __restrict__ bea,
   const float* __restrict__ w2a, const float* __restrict__ b2a,
   const float* __restrict__ w1b, const float* __restrict__ b1b,
   const float* __restrict__ gb,  const float* __restrict__ beb,
   const float* __restrict__ w2b, const float* __restrict__ b2b,
   const float* __restrict__ w1c, const float* __restrict__ b1c,
   const float* __restrict__ gc_, const float* __restrict__ bec,
   const float* __restrict__ w2c, const float* __restrict__ b2c,
   float* __restrict__ ws, int C) {
  __shared__ __align__(16) float act[160 * STR];
  __shared__ __align__(16) short Whi1[64 * WSTR], Wlo1[64 * WSTR];
  __shared__ __align__(16) short Whi2[32 * WSTR], Wlo2[32 * WSTR];
  __shared__ float vb1[64], vg[64], vbe[64], vb2[64];

  const int tid = threadIdx.x;
  const int lane = tid & 63;
  const int wave = tid >> 6;          // 0..4
  const int col = lane & 15;
  const int quad = lane >> 4;
  const int base = blockIdx.x * 160;  // node base
  const int mt0 = wave * 2 * 16;      // first M-tile row base (in-block)

  // ---- phase 0: load x (cols 0..15) + zero cols 16..31; stage pre-W1 ----
  {
    const float4* x4 = (const float4*)x;
    float4 z4 = {0.f, 0.f, 0.f, 0.f};
    for (int i = tid; i < 640; i += 320) {
      int row = i >> 2, e = i & 3;
      *(float4*)(act + row * STR + e * 4) = x4[(long)(base + row) * 4 + e];
      *(float4*)(act + row * STR + 16 + e * 4) = z4;
    }
    stageW(pw1, Whi1, Wlo1, 16, 64, tid, 320);
    for (int i = tid; i < 64 * 16; i += 320) {       // zero K rows 16..31
      int f = i >> 4, k = 16 + (i & 15);
      Whi1[f * WSTR + k] = 0; Wlo1[f * WSTR + k] = 0;
    }
    stageVec(pb1, vb1, 64, tid, 320);
    stageVec(pg, vg, 64, tid, 320);
    stageVec(pbe, vbe, 64, tid, 320);
  }
  __syncthreads();

  // ---- pre-MLP stage 1: 16(->32 padded) -> 64, LN, ReLU ----
#pragma unroll
  for (int h = 0; h < 2; ++h) {
    v4f acc[4];
    mm_frag<4, 1>(act, mt0 + h * 16, Whi1, Wlo1, vb1, col, quad, acc);
    ln_relu_write(act, mt0 + h * 16, col, quad, acc, vg, vbe);
  }
  __syncthreads();

  // ---- pre-MLP stage 2: 64 -> 64 (no LN) ----
  stageW(pw2, Whi1, Wlo1, 64, 64, tid, 320);
  stageVec(pb2, vb1, 64, tid, 320);
  __syncthreads();
#pragma unroll
  for (int h = 0; h < 2; ++h) {
    v4f acc[4];
    mm_frag<4, 2>(act, mt0 + h * 16, Whi1, Wlo1, vb1, col, quad, acc);
    plain_write<4>(act, mt0 + h * 16, col, quad, acc);
  }
  __syncthreads();

  // ---- 3 subgraph layers ----
  const float* W1s[3] = {w1a, w1b, w1c};
  const float* B1s[3] = {b1a, b1b, b1c};
  const float* Gs[3]  = {ga, gb, gc_};
  const float* BEs[3] = {bea, beb, bec};
  const float* W2s[3] = {w2a, w2b, w2c};
  const float* B2s[3] = {b2a, b2b, b2c};

  for (int L = 0; L < 3; ++L) {
    stageW(W1s[L], Whi1, Wlo1, 64, 64, tid, 320);
    stageW(W2s[L], Whi2, Wlo2, 64, 32, tid, 320);
    stageVec(B1s[L], vb1, 64, tid, 320);
    stageVec(Gs[L], vg, 64, tid, 320);
    stageVec(BEs[L], vbe, 64, tid, 320);
    stageVec(B2s[L], vb2, 32, tid, 320);
    __syncthreads();
#pragma unroll
    for (int h = 0; h < 2; ++h) {
      v4f acc[4];
      mm_frag<4, 2>(act, mt0 + h * 16, Whi1, Wlo1, vb1, col, quad, acc);
      ln_relu_write(act, mt0 + h * 16, col, quad, acc, vg, vbe);
      v4f hcc[2];
      mm_frag<2, 2>(act, mt0 + h * 16, Whi2, Wlo2, vb2, col, quad, hcc);
      plain_write<2>(act, mt0 + h * 16, col, quad, hcc);
    }
    __syncthreads();
    // pooling: 8 clusters x 32 feats
    if (tid < 256) {
      const int cl = tid >> 5, j = tid & 31;
      const int rb = cl * 20;
      float m = act[rb * STR + j];
#pragma unroll
      for (int r = 1; r < 20; ++r) m = fmaxf(m, act[(rb + r) * STR + j]);
      if (L < 2) {
#pragma unroll
        for (int r = 0; r < 20; ++r) act[(rb + r) * STR + 32 + j] = m;
      } else {
        // segmax(concat[h, pooled]) == [pooled, pooled]
        const long gc = (long)blockIdx.x * 8 + cl;
        if (gc < C) { ws[gc * 64 + j] = m; ws[gc * 64 + 32 + j] = m; }
      }
    }
    // next loop's stage happens after this implicit region; barrier at top via:
    if (L < 2) __syncthreads();
  }
}

// Output MLP over C rows: 64 -> 64 LN ReLU -> 128, L2-normalize; + batch_out.
__global__ void __launch_bounds__(256, 2)
kB(const float* __restrict__ ws, const int* __restrict__ batch,
   const float* __restrict__ ow1, const float* __restrict__ ob1,
   const float* __restrict__ og,  const float* __restrict__ obe,
   const float* __restrict__ ow2, const float* __restrict__ ob2,
   float* __restrict__ out, int C) {
  __shared__ __align__(16) float act[64 * STR];
  __shared__ __align__(16) short Whi[128 * WSTR], Wlo[128 * WSTR];
  __shared__ float vb[128], vg[64], vbe[64];

  const int tid = threadIdx.x;
  const int lane = tid & 63;
  const int wave = tid >> 6;      // 0..3 -> M-tile
  const int col = lane & 15;
  const int quad = lane >> 4;
  const long base = (long)blockIdx.x * 64;
  const int mtb = wave * 16;

  {
    const float4* w4 = (const float4*)ws;
    float4 z4 = {0.f, 0.f, 0.f, 0.f};
    for (int i = tid; i < 64 * 16; i += 256) {
      int row = i >> 4, e = i & 15;
      long r = base + row;
      *(float4*)(act + row * STR + e * 4) = (r < C) ? w4[r * 16 + e] : z4;
    }
    stageW(ow1, Whi, Wlo, 64, 64, tid, 256);
    stageVec(ob1, vb, 64, tid, 256);
    stageVec(og, vg, 64, tid, 256);
    stageVec(obe, vbe, 64, tid, 256);
  }
  __syncthreads();
  {
    v4f acc[4];
    mm_frag<4, 2>(act, mtb, Whi, Wlo, vb, col, quad, acc);
    ln_relu_write(act, mtb, col, quad, acc, vg, vbe);
  }
  __syncthreads();
  stageW(ow2, Whi, Wlo, 64, 128, tid, 256);
  stageVec(ob2, vb, 128, tid, 256);
  __syncthreads();
  {
    v4f acc[8];
    mm_frag<8, 2>(act, mtb, Whi, Wlo, vb, col, quad, acc);
    float q[4];
#pragma unroll
    for (int r = 0; r < 4; ++r) {
      float s = 0.f;
#pragma unroll
      for (int t = 0; t < 8; ++t) s = fmaf(acc[t][r], acc[t][r], s);
      q[r] = s;
    }
#pragma unroll
    for (int m = 1; m <= 8; m <<= 1)
#pragma unroll
      for (int r = 0; r < 4; ++r) q[r] += __shfl_xor(q[r], m);
    float inv[4];
#pragma unroll
    for (int r = 0; r < 4; ++r) inv[r] = 1.0f / fmaxf(sqrtf(q[r]), 1e-12f);
#pragma unroll
    for (int r = 0; r < 4; ++r) {
      const long row = base + mtb + quad * 4 + r;
      if (row < C) {
#pragma unroll
        for (int t = 0; t < 8; ++t)
          out[row * 128 + t * 16 + col] = acc[t][r] * inv[r];
      }
    }
  }
  {
    const long r = base + tid;
    if (tid < 64 && r < C) out[(long)C * 128 + r] = (float)batch[r * 20];
  }
}

extern "C" void kernel_launch(void* const* d_in, const int* in_sizes, int n_in,
                              void* d_out, int out_size, void* d_ws, size_t ws_size,
                              hipStream_t stream) {
  const float* x     = (const float*)d_in[0];
  const int*   batch = (const int*)d_in[2];
  const float* pw1 = (const float*)d_in[3];
  const float* pb1 = (const float*)d_in[4];
  const float* pg  = (const float*)d_in[5];
  const float* pbe = (const float*)d_in[6];
  const float* pw2 = (const float*)d_in[7];
  const float* pb2 = (const float*)d_in[8];
  const float* w1a = (const float*)d_in[9];
  const float* b1a = (const float*)d_in[10];
  const float* ga  = (const float*)d_in[11];
  const float* bea = (const float*)d_in[12];
  const float* w2a = (const float*)d_in[13];
  const float* b2a = (const float*)d_in[14];
  const float* w1b = (const float*)d_in[15];
  const float* b1b = (const float*)d_in[16];
  const float* gb  = (const float*)d_in[17];
  const float* beb = (const float*)d_in[18];
  const float* w2b = (const float*)d_in[19];
  const float* b2b = (const float*)d_in[20];
  const float* w1c = (const float*)d_in[21];
  const float* b1c = (const float*)d_in[22];
  const float* gc  = (const float*)d_in[23];
  const float* bec = (const float*)d_in[24];
  const float* w2c = (const float*)d_in[25];
  const float* b2c = (const float*)d_in[26];
  const float* ow1 = (const float*)d_in[27];
  const float* ob1 = (const float*)d_in[28];
  const float* og  = (const float*)d_in[29];
  const float* obe = (const float*)d_in[30];
  const float* ow2 = (const float*)d_in[31];
  const float* ob2 = (const float*)d_in[32];

  const int N = in_sizes[0] / 16;
  const int C = N / 20;
  float* ws  = (float*)d_ws;
  float* out = (float*)d_out;

  const int blocksA = (C + 7) / 8;     // 8 clusters (160 nodes) per block
  hipLaunchKernelGGL(kA, dim3(blocksA), dim3(320), 0, stream,
                     x, pw1, pb1, pg, pbe, pw2, pb2,
                     w1a, b1a, ga, bea, w2a, b2a,
                     w1b, b1b, gb, beb, w2b, b2b,
                     w1c, b1c, gc, bec, w2c, b2c,
                     ws, C);

  const int blocksB = (C + 63) / 64;   // 64 rows per block (4 waves x 16)
  hipLaunchKernelGGL(kB, dim3(blocksB), dim3(256), 0, stream,
                     ws, batch, ow1, ob1, og, obe, ow2, ob2, out, C);
}

// Round 5
// 458.684 us; speedup vs baseline: 3.6452x; 1.6916x over previous
//
#include <hip/hip_runtime.h>

// ---------------------------------------------------------------------------
// MFMA 16x16x32 bf16, activations AND weights bf16 (RNE) in LDS.
// kA block = 320 thr (5 waves) = 160 nodes = 8 clusters; wave owns 2 M-tiles.
// act: short[160][72] (row stride 72 shorts = 36 floats; (col*36+quad*4)%32
// covers banks per 8-lane group -> conflict-free b128).
// Weights staged transposed [F][72] bf16 via lane=f vectorized writes
// (conflict-free). B-frags shared across the wave's 2 tiles per ks.
// LayerNorm 16-lane reduction via DPP (quad_perm/row_mirror) - zero DS ops.
// segmax(concat[h,pooled]) == [pooled,pooled] shortcut for the last layer.
// ---------------------------------------------------------------------------

#define ASTR 72   // act row stride (shorts)
#define WSTR 72   // weight row stride (shorts)

typedef short v8s __attribute__((ext_vector_type(8)));
typedef float v4f __attribute__((ext_vector_type(4)));

#define MFMA __builtin_amdgcn_mfma_f32_16x16x32_bf16

__device__ __forceinline__ short bfb(float v) {
  __bf16 b = (__bf16)v;
  return __builtin_bit_cast(short, b);
}

template <int CTRL>
__device__ __forceinline__ float dppadd(float x) {
  int xi = __builtin_bit_cast(int, x);
  int yi = __builtin_amdgcn_update_dpp(xi, xi, CTRL, 0xF, 0xF, false);
  return x + __builtin_bit_cast(float, yi);
}
// all-reduce sum over the 16-lane DPP row (our col group)
__device__ __forceinline__ float sum16(float x) {
  x = dppadd<0xB1>(x);   // quad_perm [1,0,3,2]  (xor 1)
  x = dppadd<0x4E>(x);   // quad_perm [2,3,0,1]  (xor 2)
  x = dppadd<0x141>(x);  // row_half_mirror      (pairs quads 0-1 / 2-3)
  x = dppadd<0x140>(x);  // row_mirror           (pairs halves)
  return x;
}

// Stage W[K][F] f32 global -> dst[f][k] bf16 LDS (transposed), K padded to Kpad.
template <int F>
__device__ __forceinline__ void stageWbf(const float* __restrict__ W, short* dst,
                                         int K, int Kpad, int tid, int nthr) {
  const int total = F * (Kpad >> 3);
  for (int i = tid; i < total; i += nthr) {
    const int f = i & (F - 1);
    const int kq = i / F;
    v8s h;
#pragma unroll
    for (int j = 0; j < 8; ++j) {
      const int k = kq * 8 + j;
      h[j] = bfb((k < K) ? W[k * F + f] : 0.f);
    }
    *(v8s*)(dst + f * WSTR + kq * 8) = h;
  }
}

__device__ __forceinline__ void stageVec(const float* __restrict__ src,
                                         float* dst, int n, int tid, int nthr) {
  for (int i = tid; i < n; i += nthr) dst[i] = src[i];
}

// Two M-tiles (mt0, mt0+16), B-frag loaded once per (ks,t), shared by tiles.
template <int NT, int KS>
__device__ __forceinline__ void mm2tile(const short* actb, int mt0,
                                        const short* W, const float* bias,
                                        int col, int quad,
                                        v4f* acc0, v4f* acc1) {
#pragma unroll
  for (int t = 0; t < NT; ++t) {
    float bv = bias[t * 16 + col];
    acc0[t] = (v4f){bv, bv, bv, bv};
    acc1[t] = acc0[t];
  }
#pragma unroll
  for (int ks = 0; ks < KS; ++ks) {
    const v8s a0 = *(const v8s*)(actb + (mt0 + col) * ASTR + ks * 32 + quad * 8);
    const v8s a1 = *(const v8s*)(actb + (mt0 + 16 + col) * ASTR + ks * 32 + quad * 8);
#pragma unroll
    for (int t = 0; t < NT; ++t) {
      const v8s b = *(const v8s*)(W + (t * 16 + col) * WSTR + ks * 32 + quad * 8);
      acc0[t] = MFMA(a0, b, acc0[t], 0, 0, 0);
      acc1[t] = MFMA(a1, b, acc1[t], 0, 0, 0);
    }
  }
}

// Single M-tile variant (kB).
template <int NT, int KS>
__device__ __forceinline__ void mm1tile(const short* actb, int mt0,
                                        const short* W, const float* bias,
                                        int col, int quad, v4f* acc) {
#pragma unroll
  for (int t = 0; t < NT; ++t) {
    float bv = bias[t * 16 + col];
    acc[t] = (v4f){bv, bv, bv, bv};
  }
#pragma unroll
  for (int ks = 0; ks < KS; ++ks) {
    const v8s a = *(const v8s*)(actb + (mt0 + col) * ASTR + ks * 32 + quad * 8);
#pragma unroll
    for (int t = 0; t < NT; ++t) {
      const v8s b = *(const v8s*)(W + (t * 16 + col) * WSTR + ks * 32 + quad * 8);
      acc[t] = MFMA(a, b, acc[t], 0, 0, 0);
    }
  }
}

// LayerNorm(64)+ReLU on one tile's C-frags; write bf16 rows to act.
__device__ __forceinline__ void ln_relu_write(short* actb, int mtb, int col,
                                              int quad, v4f* acc,
                                              const float* g, const float* be) {
  float mu[4], sq[4], rs[4];
#pragma unroll
  for (int r = 0; r < 4; ++r) {
    mu[r] = acc[0][r] + acc[1][r] + acc[2][r] + acc[3][r];
    sq[r] = fmaf(acc[0][r], acc[0][r], fmaf(acc[1][r], acc[1][r],
            fmaf(acc[2][r], acc[2][r], acc[3][r] * acc[3][r])));
  }
#pragma unroll
  for (int r = 0; r < 4; ++r) {
    mu[r] = sum16(mu[r]);
    sq[r] = sum16(sq[r]);
  }
#pragma unroll
  for (int r = 0; r < 4; ++r) {
    float m_ = mu[r] * (1.0f / 64.0f);
    float v_ = sq[r] * (1.0f / 64.0f) - m_ * m_;
    mu[r] = m_;
    rs[r] = rsqrtf(v_ + 1e-5f);
  }
#pragma unroll
  for (int t = 0; t < 4; ++t) {
    float gv = g[t * 16 + col], bv = be[t * 16 + col];
#pragma unroll
    for (int r = 0; r < 4; ++r) {
      float val = fmaf((acc[t][r] - mu[r]) * rs[r], gv, bv);
      actb[(mtb + quad * 4 + r) * ASTR + t * 16 + col] = bfb(fmaxf(val, 0.f));
    }
  }
}

template <int NT>
__device__ __forceinline__ void plain_write(short* actb, int mtb, int col,
                                            int quad, v4f* acc) {
#pragma unroll
  for (int t = 0; t < NT; ++t)
#pragma unroll
    for (int r = 0; r < 4; ++r)
      actb[(mtb + quad * 4 + r) * ASTR + t * 16 + col] = bfb(acc[t][r]);
}

__global__ void __launch_bounds__(320, 4)
kA(const float* __restrict__ x,
   const float* __restrict__ pw1, const float* __restrict__ pb1,
   const float* __restrict__ pg,  const float* __restrict__ pbe,
   const float* __restrict__ pw2, const float* __restrict__ pb2,
   const float* __restrict__ w1a, const float* __restrict__ b1a,
   const float* __restrict__ ga,  const float* __restrict__ bea,
   const float* __restrict__ w2a, const float* __restrict__ b2a,
   const float* __restrict__ w1b, const float* __restrict__ b1b,
   const float* __restrict__ gb,  const float* __restrict__ beb,
   const float* __restrict__ w2b, const float* __restrict__ b2b,
   const float* __restrict__ w1c, const float* __restrict__ b1c,
   const float* __restrict__ gc_, const float* __restrict__ bec,
   const float* __restrict__ w2c, const float* __restrict__ b2c,
   short* __restrict__ ws16, int C) {
  __shared__ __align__(16) short act[160 * ASTR];
  __shared__ __align__(16) short W1[64 * WSTR];
  __shared__ __align__(16) short W2[32 * WSTR];
  __shared__ float vb1[64], vg[64], vbe[64], vb2[64];

  const int tid = threadIdx.x;
  const int lane = tid & 63;
  const int wave = tid >> 6;          // 0..4
  const int col = lane & 15;
  const int quad = lane >> 4;
  const int base = blockIdx.x * 160;  // node base (grid sized exactly)
  const int mt0 = wave * 32;          // wave's first tile row

  // ---- phase 0: x -> act bf16 (cols 0..15) + zero cols 16..31; stage pre-W1
  {
    const float4* x4 = (const float4*)x;
    for (int i = tid; i < 640; i += 320) {
      const int row = i >> 2, e = i & 3;
      float4 v = x4[(long)(base + row) * 4 + e];
      short4 s = {bfb(v.x), bfb(v.y), bfb(v.z), bfb(v.w)};
      *(short4*)(act + row * ASTR + e * 4) = s;
      *(short4*)(act + row * ASTR + 16 + e * 4) = (short4){0, 0, 0, 0};
    }
    stageWbf<64>(pw1, W1, 16, 32, tid, 320);
    stageVec(pb1, vb1, 64, tid, 320);
    stageVec(pg, vg, 64, tid, 320);
    stageVec(pbe, vbe, 64, tid, 320);
  }
  __syncthreads();

  // ---- pre-MLP stage 1: 16(pad 32) -> 64, LN, ReLU ----
  {
    v4f a0[4], a1[4];
    mm2tile<4, 1>(act, mt0, W1, vb1, col, quad, a0, a1);
    ln_relu_write(act, mt0, col, quad, a0, vg, vbe);
    ln_relu_write(act, mt0 + 16, col, quad, a1, vg, vbe);
  }
  __syncthreads();
  // ---- pre-MLP stage 2: 64 -> 64 ----
  stageWbf<64>(pw2, W1, 64, 64, tid, 320);
  stageVec(pb2, vb1, 64, tid, 320);
  __syncthreads();
  {
    v4f a0[4], a1[4];
    mm2tile<4, 2>(act, mt0, W1, vb1, col, quad, a0, a1);
    plain_write<4>(act, mt0, col, quad, a0);
    plain_write<4>(act, mt0 + 16, col, quad, a1);
  }

  // ---- 3 subgraph layers ----
  const float* W1s[3] = {w1a, w1b, w1c};
  const float* B1s[3] = {b1a, b1b, b1c};
  const float* Gs[3]  = {ga, gb, gc_};
  const float* BEs[3] = {bea, beb, bec};
  const float* W2s[3] = {w2a, w2b, w2c};
  const float* B2s[3] = {b2a, b2b, b2c};

  for (int L = 0; L < 3; ++L) {
    __syncthreads();                       // done reading previous W1
    stageWbf<64>(W1s[L], W1, 64, 64, tid, 320);
    stageWbf<32>(W2s[L], W2, 64, 64, tid, 320);
    stageVec(B1s[L], vb1, 64, tid, 320);
    stageVec(Gs[L], vg, 64, tid, 320);
    stageVec(BEs[L], vbe, 64, tid, 320);
    stageVec(B2s[L], vb2, 32, tid, 320);
    __syncthreads();
    {
      v4f a0[4], a1[4];
      mm2tile<4, 2>(act, mt0, W1, vb1, col, quad, a0, a1);
      ln_relu_write(act, mt0, col, quad, a0, vg, vbe);
      ln_relu_write(act, mt0 + 16, col, quad, a1, vg, vbe);
      v4f h0[2], h1[2];
      mm2tile<2, 2>(act, mt0, W2, vb2, col, quad, h0, h1);
      plain_write<2>(act, mt0, col, quad, h0);
      plain_write<2>(act, mt0 + 16, col, quad, h1);
    }
    __syncthreads();                       // h visible for pooling
    // pool: 8 clusters x 16 short2-cols; reads cols 0..31, writes 32..63
    if (tid < 128) {
      const int cl = tid >> 4, jp = tid & 15;
      const uint* actU = (const uint*)act;
      const int rb = cl * 20;
      float m0 = -3.4e38f, m1 = -3.4e38f;
#pragma unroll
      for (int r = 0; r < 20; ++r) {
        uint v = actU[(rb + r) * (ASTR / 2) + jp];
        m0 = fmaxf(m0, __builtin_bit_cast(float, v << 16));
        m1 = fmaxf(m1, __builtin_bit_cast(float, v & 0xFFFF0000u));
      }
      const uint pv = (uint)(unsigned short)bfb(m0) | ((uint)(unsigned short)bfb(m1) << 16);
      if (L < 2) {
        uint* actW = (uint*)act;
#pragma unroll
        for (int r = 0; r < 20; ++r) actW[(rb + r) * (ASTR / 2) + 16 + jp] = pv;
      } else {
        // segmax(concat[h, pooled]) == [pooled, pooled]
        const long gc = (long)blockIdx.x * 8 + cl;
        uint* wsU = (uint*)ws16;
        wsU[gc * 32 + jp] = pv;
        wsU[gc * 32 + 16 + jp] = pv;
      }
    }
  }
}

// Output MLP over C rows: 64 -> 64 LN ReLU -> 128, L2-normalize; + batch_out.
// Single __syncthreads(): all staging up front, then pure same-wave compute.
__global__ void __launch_bounds__(256, 4)
kB(const short* __restrict__ ws16, const int* __restrict__ batch,
   const float* __restrict__ ow1, const float* __restrict__ ob1,
   const float* __restrict__ og,  const float* __restrict__ obe,
   const float* __restrict__ ow2, const float* __restrict__ ob2,
   float* __restrict__ out, int C) {
  __shared__ __align__(16) short act[64 * ASTR];
  __shared__ __align__(16) short W1[64 * WSTR];
  __shared__ __align__(16) short W2[128 * WSTR];
  __shared__ float vb1[64], vg[64], vbe[64], vb2[128];

  const int tid = threadIdx.x;
  const int lane = tid & 63;
  const int wave = tid >> 6;      // 0..3 -> M-tile
  const int col = lane & 15;
  const int quad = lane >> 4;
  const long base = (long)blockIdx.x * 64;
  const int mtb = wave * 16;

  {
    for (int i = tid; i < 64 * 8; i += 256) {
      const int row = i >> 3, e = i & 7;
      const long r = base + row;
      v8s v = (r < C) ? *(const v8s*)(ws16 + r * 64 + e * 8)
                      : (v8s){0, 0, 0, 0, 0, 0, 0, 0};
      *(v8s*)(act + row * ASTR + e * 8) = v;
    }
    stageWbf<64>(ow1, W1, 64, 64, tid, 256);
    stageWbf<128>(ow2, W2, 64, 64, tid, 256);
    stageVec(ob1, vb1, 64, tid, 256);
    stageVec(og, vg, 64, tid, 256);
    stageVec(obe, vbe, 64, tid, 256);
    stageVec(ob2, vb2, 128, tid, 256);
  }
  __syncthreads();
  {
    v4f acc[4];
    mm1tile<4, 2>(act, mtb, W1, vb1, col, quad, acc);
    ln_relu_write(act, mtb, col, quad, acc, vg, vbe);   // same-wave rows
  }
  {
    v4f acc[8];
    mm1tile<8, 2>(act, mtb, W2, vb2, col, quad, acc);
    float q[4];
#pragma unroll
    for (int r = 0; r < 4; ++r) {
      float s = 0.f;
#pragma unroll
      for (int t = 0; t < 8; ++t) s = fmaf(acc[t][r], acc[t][r], s);
      q[r] = sum16(s);
    }
    float inv[4];
#pragma unroll
    for (int r = 0; r < 4; ++r) inv[r] = 1.0f / fmaxf(sqrtf(q[r]), 1e-12f);
#pragma unroll
    for (int r = 0; r < 4; ++r) {
      const long row = base + mtb + quad * 4 + r;
      if (row < C) {
#pragma unroll
        for (int t = 0; t < 8; ++t)
          out[row * 128 + t * 16 + col] = acc[t][r] * inv[r];
      }
    }
  }
  if (tid < 64) {
    const long r = base + tid;
    if (r < C) out[(long)C * 128 + r] = (float)batch[r * 20];
  }
}

extern "C" void kernel_launch(void* const* d_in, const int* in_sizes, int n_in,
                              void* d_out, int out_size, void* d_ws, size_t ws_size,
                              hipStream_t stream) {
  const float* x     = (const float*)d_in[0];
  const int*   batch = (const int*)d_in[2];
  const float* pw1 = (const float*)d_in[3];
  const float* pb1 = (const float*)d_in[4];
  const float* pg  = (const float*)d_in[5];
  const float* pbe = (const float*)d_in[6];
  const float* pw2 = (const float*)d_in[7];
  const float* pb2 = (const float*)d_in[8];
  const float* w1a = (const float*)d_in[9];
  const float* b1a = (const float*)d_in[10];
  const float* ga  = (const float*)d_in[11];
  const float* bea = (const float*)d_in[12];
  const float* w2a = (const float*)d_in[13];
  const float* b2a = (const float*)d_in[14];
  const float* w1b = (const float*)d_in[15];
  const float* b1b = (const float*)d_in[16];
  const float* gb  = (const float*)d_in[17];
  const float* beb = (const float*)d_in[18];
  const float* w2b = (const float*)d_in[19];
  const float* b2b = (const float*)d_in[20];
  const float* w1c = (const float*)d_in[21];
  const float* b1c = (const float*)d_in[22];
  const float* gc  = (const float*)d_in[23];
  const float* bec = (const float*)d_in[24];
  const float* w2c = (const float*)d_in[25];
  const float* b2c = (const float*)d_in[26];
  const float* ow1 = (const float*)d_in[27];
  const float* ob1 = (const float*)d_in[28];
  const float* og  = (const float*)d_in[29];
  const float* obe = (const float*)d_in[30];
  const float* ow2 = (const float*)d_in[31];
  const float* ob2 = (const float*)d_in[32];

  const int N = in_sizes[0] / 16;
  const int C = N / 20;
  short* ws16 = (short*)d_ws;
  float* out = (float*)d_out;

  const int blocksA = (C + 7) / 8;     // 8 clusters (160 nodes) per block
  hipLaunchKernelGGL(kA, dim3(blocksA), dim3(320), 0, stream,
                     x, pw1, pb1, pg, pbe, pw2, pb2,
                     w1a, b1a, ga, bea, w2a, b2a,
                     w1b, b1b, gb, beb, w2b, b2b,
                     w1c, b1c, gc, bec, w2c, b2c,
                     ws16, C);

  const int blocksB = (C + 63) / 64;   // 64 rows per block (4 waves x 16)
  hipLaunchKernelGGL(kB, dim3(blocksB), dim3(256), 0, stream,
                     ws16, batch, ow1, ob1, og, obe, ow2, ob2, out, C);
}

// Round 6
// 324.677 us; speedup vs baseline: 5.1498x; 1.4127x over previous
//
#include <hip/hip_runtime.h>

// ---------------------------------------------------------------------------
// Barrier-free wave-autonomous design. kT pre-transposes all weights into
// d_ws as bf16 in B-fragment layout (W^T[f][k], row stride Kpad). kF: each
// wave owns 4 clusters = 80 nodes = 5 M-tiles in a private LDS slab; weight
// fragments are global loads (L1/L2-hot); pooling, out-MLP, normalize and
// batch_out all intra-wave. ZERO __syncthreads.
// Fragment maps (verified R3/R5): A: m=lane&15, k=quad*8+j; B: n=lane&15,
// k=quad*8+j; C/D: col(n)=lane&15, row(m)=quad*4+reg.
// ---------------------------------------------------------------------------

#define ASTR 72   // act row stride in shorts; b128 reads hit all 32 banks/8 phases

typedef short v8s __attribute__((ext_vector_type(8)));
typedef float v4f __attribute__((ext_vector_type(4)));

#define MFMA __builtin_amdgcn_mfma_f32_16x16x32_bf16

// ws layout (offsets in shorts)
#define OFF_PW1 0                        // 64 x 32 (K=16 zero-padded to 32)
#define OFF_PW2 2048                     // 64 x 64
#define OFF_LW1(L) (6144 + (L) * 6144)   // 64 x 64
#define OFF_LW2(L) (OFF_LW1(L) + 4096)   // 32 x 64
#define OFF_OW1 24576                    // 64 x 64
#define OFF_OW2 28672                    // 128 x 64  (end 36864 shorts = 72 KB)

__device__ __forceinline__ short bfb(float v) {
  __bf16 b = (__bf16)v;
  return __builtin_bit_cast(short, b);
}

template <int CTRL>
__device__ __forceinline__ float dppadd(float x) {
  int xi = __builtin_bit_cast(int, x);
  int yi = __builtin_amdgcn_update_dpp(xi, xi, CTRL, 0xF, 0xF, false);
  return x + __builtin_bit_cast(float, yi);
}
__device__ __forceinline__ float sum16(float x) {
  x = dppadd<0xB1>(x);   // quad_perm xor1
  x = dppadd<0x4E>(x);   // quad_perm xor2
  x = dppadd<0x141>(x);  // row_half_mirror
  x = dppadd<0x140>(x);  // row_mirror
  return x;
}

// LayerNorm(64)+ReLU on one tile's C-frags (g/be in regs); bf16 rows to act.
__device__ __forceinline__ void ln_relu_write(short* A, int mtb, int col,
                                              int quad, v4f* acc,
                                              const float* gv, const float* bev) {
  float mu[4], sq[4], rs[4];
#pragma unroll
  for (int r = 0; r < 4; ++r) {
    mu[r] = acc[0][r] + acc[1][r] + acc[2][r] + acc[3][r];
    sq[r] = fmaf(acc[0][r], acc[0][r], fmaf(acc[1][r], acc[1][r],
            fmaf(acc[2][r], acc[2][r], acc[3][r] * acc[3][r])));
  }
#pragma unroll
  for (int r = 0; r < 4; ++r) { mu[r] = sum16(mu[r]); sq[r] = sum16(sq[r]); }
#pragma unroll
  for (int r = 0; r < 4; ++r) {
    float m_ = mu[r] * (1.0f / 64.0f);
    float v_ = sq[r] * (1.0f / 64.0f) - m_ * m_;
    mu[r] = m_;
    rs[r] = rsqrtf(v_ + 1e-5f);
  }
#pragma unroll
  for (int t = 0; t < 4; ++t) {
#pragma unroll
    for (int r = 0; r < 4; ++r) {
      float val = fmaf((acc[t][r] - mu[r]) * rs[r], gv[t], bev[t]);
      A[(mtb + quad * 4 + r) * ASTR + t * 16 + col] = bfb(fmaxf(val, 0.f));
    }
  }
}

template <int NT>
__device__ __forceinline__ void plain_write(short* A, int mtb, int col,
                                            int quad, v4f* acc) {
#pragma unroll
  for (int t = 0; t < NT; ++t)
#pragma unroll
    for (int r = 0; r < 4; ++r)
      A[(mtb + quad * 4 + r) * ASTR + t * 16 + col] = bfb(acc[t][r]);
}

// ---- kT: transpose weights into bf16 B-fragment layout in ws ----
__global__ void kT(const float* __restrict__ pw1, const float* __restrict__ pw2,
                   const float* __restrict__ w1a, const float* __restrict__ w2a,
                   const float* __restrict__ w1b, const float* __restrict__ w2b,
                   const float* __restrict__ w1c, const float* __restrict__ w2c,
                   const float* __restrict__ ow1, const float* __restrict__ ow2,
                   short* __restrict__ ws) {
  const float* W; int K, F, Kpad, off;
  switch (blockIdx.x) {
    case 0: W = pw1; K = 16; F = 64;  Kpad = 32; off = OFF_PW1; break;
    case 1: W = pw2; K = 64; F = 64;  Kpad = 64; off = OFF_PW2; break;
    case 2: W = w1a; K = 64; F = 64;  Kpad = 64; off = OFF_LW1(0); break;
    case 3: W = w2a; K = 64; F = 32;  Kpad = 64; off = OFF_LW2(0); break;
    case 4: W = w1b; K = 64; F = 64;  Kpad = 64; off = OFF_LW1(1); break;
    case 5: W = w2b; K = 64; F = 32;  Kpad = 64; off = OFF_LW2(1); break;
    case 6: W = w1c; K = 64; F = 64;  Kpad = 64; off = OFF_LW1(2); break;
    case 7: W = w2c; K = 64; F = 32;  Kpad = 64; off = OFF_LW2(2); break;
    case 8: W = ow1; K = 64; F = 64;  Kpad = 64; off = OFF_OW1; break;
    default: W = ow2; K = 64; F = 128; Kpad = 64; off = OFF_OW2; break;
  }
  const int total = F * (Kpad >> 3);
  for (int i = threadIdx.x; i < total; i += blockDim.x) {
    const int f = i % F;
    const int kq = i / F;
    v8s h;
#pragma unroll
    for (int j = 0; j < 8; ++j) {
      const int k = kq * 8 + j;
      h[j] = bfb((k < K) ? W[k * F + f] : 0.f);
    }
    *(v8s*)(ws + off + f * Kpad + kq * 8) = h;
  }
}

// ---- kF: the whole network, one wave = 4 clusters, zero barriers ----
__global__ void __launch_bounds__(256, 3)
kF(const float* __restrict__ x, const int* __restrict__ batch,
   const short* __restrict__ wsW,
   const float* __restrict__ pb1, const float* __restrict__ pg,
   const float* __restrict__ pbe, const float* __restrict__ pb2,
   const float* __restrict__ b1a, const float* __restrict__ ga,
   const float* __restrict__ bea, const float* __restrict__ b2a,
   const float* __restrict__ b1b, const float* __restrict__ gb,
   const float* __restrict__ beb, const float* __restrict__ b2b,
   const float* __restrict__ b1c, const float* __restrict__ gc_,
   const float* __restrict__ bec, const float* __restrict__ b2c,
   const float* __restrict__ ob1, const float* __restrict__ og,
   const float* __restrict__ obe, const float* __restrict__ ob2,
   float* __restrict__ out, int C) {
  __shared__ __align__(16) short act[4 * 80 * ASTR];
  const int tid = threadIdx.x;
  const int lane = tid & 63;
  const int wave = tid >> 6;
  const int col = lane & 15;
  const int quad = lane >> 4;
  const int cbase = blockIdx.x * 16 + wave * 4;
  if (cbase >= C) return;
  const int nc = min(4, C - cbase);
  const int nrows = nc * 20;
  const int ntiles = (nrows + 15) >> 4;
  short* A = act + wave * 80 * ASTR;

  // ---- load x -> bf16 cols 0..15, zero cols 16..31 ----
  {
    const float4* x4 = (const float4*)x;
    const long nb = (long)cbase * 20;
    const short4 z = {0, 0, 0, 0};
    for (int i = lane; i < nrows * 4; i += 64) {
      const int row = i >> 2, e = i & 3;
      float4 v = x4[(nb + row) * 4 + e];
      short4 s = {bfb(v.x), bfb(v.y), bfb(v.z), bfb(v.w)};
      *(short4*)(A + row * ASTR + e * 4) = s;
      *(short4*)(A + row * ASTR + 16 + e * 4) = z;
    }
    if (nrows < ntiles * 16) {   // zero-fill tail rows (partial wave)
      for (int i = lane; i < (ntiles * 16 - nrows) * 18; i += 64) {
        const int row = nrows + i / 18, e = i % 18;
        *(short4*)(A + row * ASTR + e * 4) = z;
      }
    }
  }

  // ---- pre-MLP stage 1: 16(pad32) -> 64, LN, ReLU ----
  {
    v8s B[4]; float bv[4], gv[4], bev[4];
#pragma unroll
    for (int t = 0; t < 4; ++t) {
      B[t] = *(const v8s*)(wsW + OFF_PW1 + (t * 16 + col) * 32 + quad * 8);
      bv[t] = pb1[t * 16 + col];
      gv[t] = pg[t * 16 + col];
      bev[t] = pbe[t * 16 + col];
    }
    for (int T = 0; T < ntiles; ++T) {
      const int mt0 = T * 16;
      const v8s a = *(const v8s*)(A + (mt0 + col) * ASTR + quad * 8);
      v4f acc[4];
#pragma unroll
      for (int t = 0; t < 4; ++t) {
        acc[t] = (v4f){bv[t], bv[t], bv[t], bv[t]};
        acc[t] = MFMA(a, B[t], acc[t], 0, 0, 0);
      }
      ln_relu_write(A, mt0, col, quad, acc, gv, bev);
    }
  }

  // ---- pre-MLP stage 2: 64 -> 64 ----
  {
    v8s B[8]; float bv[4];
#pragma unroll
    for (int t = 0; t < 4; ++t) {
#pragma unroll
      for (int ks = 0; ks < 2; ++ks)
        B[t * 2 + ks] = *(const v8s*)(wsW + OFF_PW2 + (t * 16 + col) * 64 + ks * 32 + quad * 8);
      bv[t] = pb2[t * 16 + col];
    }
    for (int T = 0; T < ntiles; ++T) {
      const int mt0 = T * 16;
      const v8s a0 = *(const v8s*)(A + (mt0 + col) * ASTR + quad * 8);
      const v8s a1 = *(const v8s*)(A + (mt0 + col) * ASTR + 32 + quad * 8);
      v4f acc[4];
#pragma unroll
      for (int t = 0; t < 4; ++t) {
        acc[t] = (v4f){bv[t], bv[t], bv[t], bv[t]};
        acc[t] = MFMA(a0, B[t * 2], acc[t], 0, 0, 0);
        acc[t] = MFMA(a1, B[t * 2 + 1], acc[t], 0, 0, 0);
      }
      plain_write<4>(A, mt0, col, quad, acc);
    }
  }

  // ---- 3 subgraph layers ----
  const float* B1p[3] = {b1a, b1b, b1c};
  const float* Gp[3]  = {ga, gb, gc_};
  const float* BEp[3] = {bea, beb, bec};
  const float* B2p[3] = {b2a, b2b, b2c};

  for (int L = 0; L < 3; ++L) {
    v8s B1[8], B2[4];
    float b1v[4], gv[4], bev[4], b2v[2];
    const short* w1 = wsW + OFF_LW1(L);
    const short* w2 = wsW + OFF_LW2(L);
#pragma unroll
    for (int t = 0; t < 4; ++t) {
#pragma unroll
      for (int ks = 0; ks < 2; ++ks)
        B1[t * 2 + ks] = *(const v8s*)(w1 + (t * 16 + col) * 64 + ks * 32 + quad * 8);
      b1v[t] = B1p[L][t * 16 + col];
      gv[t] = Gp[L][t * 16 + col];
      bev[t] = BEp[L][t * 16 + col];
    }
#pragma unroll
    for (int t = 0; t < 2; ++t) {
#pragma unroll
      for (int ks = 0; ks < 2; ++ks)
        B2[t * 2 + ks] = *(const v8s*)(w2 + (t * 16 + col) * 64 + ks * 32 + quad * 8);
      b2v[t] = B2p[L][t * 16 + col];
    }
    for (int T = 0; T < ntiles; ++T) {
      const int mt0 = T * 16;
      const v8s a0 = *(const v8s*)(A + (mt0 + col) * ASTR + quad * 8);
      const v8s a1 = *(const v8s*)(A + (mt0 + col) * ASTR + 32 + quad * 8);
      v4f acc[4];
#pragma unroll
      for (int t = 0; t < 4; ++t) {
        acc[t] = (v4f){b1v[t], b1v[t], b1v[t], b1v[t]};
        acc[t] = MFMA(a0, B1[t * 2], acc[t], 0, 0, 0);
        acc[t] = MFMA(a1, B1[t * 2 + 1], acc[t], 0, 0, 0);
      }
      ln_relu_write(A, mt0, col, quad, acc, gv, bev);
      const v8s c0 = *(const v8s*)(A + (mt0 + col) * ASTR + quad * 8);
      const v8s c1 = *(const v8s*)(A + (mt0 + col) * ASTR + 32 + quad * 8);
      v4f h[2];
#pragma unroll
      for (int t = 0; t < 2; ++t) {
        h[t] = (v4f){b2v[t], b2v[t], b2v[t], b2v[t]};
        h[t] = MFMA(c0, B2[t * 2], h[t], 0, 0, 0);
        h[t] = MFMA(c1, B2[t * 2 + 1], h[t], 0, 0, 0);
      }
      plain_write<2>(A, mt0, col, quad, h);
    }
    // ---- intra-wave pooling: lane (cl=quad? no: cl=lane>>4, jp=lane&15) ----
    {
      const int cl = quad, jp = col;       // 4 clusters x 16 uint-cols
      if (cl < nc) {
        const uint* AU = (const uint*)A;
        float m0 = -3.4e38f, m1 = -3.4e38f;
#pragma unroll
        for (int r = 0; r < 20; ++r) {
          const uint v = AU[(cl * 20 + r) * (ASTR / 2) + jp];
          m0 = fmaxf(m0, __builtin_bit_cast(float, v << 16));
          m1 = fmaxf(m1, __builtin_bit_cast(float, v & 0xFFFF0000u));
        }
        const uint pv = (uint)(unsigned short)bfb(m0) |
                        ((uint)(unsigned short)bfb(m1) << 16);
        uint* AW = (uint*)A;
        if (L < 2) {
#pragma unroll
          for (int r = 0; r < 20; ++r)
            AW[(cl * 20 + r) * (ASTR / 2) + 16 + jp] = pv;
        } else {
          // segmax(concat[h,pooled]) == [pooled,pooled] -> rows 0..3 = pooled
          AW[cl * (ASTR / 2) + jp] = pv;
          AW[cl * (ASTR / 2) + 16 + jp] = pv;
        }
      }
    }
  }

  // ---- fused output MLP on rows 0..15 (rows 0..nc-1 valid) ----
  {
    v8s B[8]; float bv[4], gv[4], bev[4];
#pragma unroll
    for (int t = 0; t < 4; ++t) {
#pragma unroll
      for (int ks = 0; ks < 2; ++ks)
        B[t * 2 + ks] = *(const v8s*)(wsW + OFF_OW1 + (t * 16 + col) * 64 + ks * 32 + quad * 8);
      bv[t] = ob1[t * 16 + col];
      gv[t] = og[t * 16 + col];
      bev[t] = obe[t * 16 + col];
    }
    const v8s a0 = *(const v8s*)(A + col * ASTR + quad * 8);
    const v8s a1 = *(const v8s*)(A + col * ASTR + 32 + quad * 8);
    v4f acc[4];
#pragma unroll
    for (int t = 0; t < 4; ++t) {
      acc[t] = (v4f){bv[t], bv[t], bv[t], bv[t]};
      acc[t] = MFMA(a0, B[t * 2], acc[t], 0, 0, 0);
      acc[t] = MFMA(a1, B[t * 2 + 1], acc[t], 0, 0, 0);
    }
    ln_relu_write(A, 0, col, quad, acc, gv, bev);
  }
  {
    v4f acc[8];
    const v8s a0 = *(const v8s*)(A + col * ASTR + quad * 8);
    const v8s a1 = *(const v8s*)(A + col * ASTR + 32 + quad * 8);
#pragma unroll
    for (int half = 0; half < 2; ++half) {
      v8s B[8];
#pragma unroll
      for (int t = 0; t < 4; ++t)
#pragma unroll
        for (int ks = 0; ks < 2; ++ks)
          B[t * 2 + ks] = *(const v8s*)(wsW + OFF_OW2 +
                            ((half * 4 + t) * 16 + col) * 64 + ks * 32 + quad * 8);
#pragma unroll
      for (int t = 0; t < 4; ++t) {
        const float bv = ob2[(half * 4 + t) * 16 + col];
        v4f a = (v4f){bv, bv, bv, bv};
        a = MFMA(a0, B[t * 2], a, 0, 0, 0);
        a = MFMA(a1, B[t * 2 + 1], a, 0, 0, 0);
        acc[half * 4 + t] = a;
      }
    }
    float inv[4];
#pragma unroll
    for (int r = 0; r < 4; ++r) {
      float s = 0.f;
#pragma unroll
      for (int t = 0; t < 8; ++t) s = fmaf(acc[t][r], acc[t][r], s);
      s = sum16(s);
      inv[r] = 1.0f / fmaxf(sqrtf(s), 1e-12f);
    }
    if (quad == 0) {
#pragma unroll
      for (int r = 0; r < 4; ++r) {
        if (r < nc) {
          const long gcl = cbase + r;
#pragma unroll
          for (int t = 0; t < 8; ++t)
            out[gcl * 128 + t * 16 + col] = acc[t][r] * inv[r];
          if (col == 0) out[(long)C * 128 + gcl] = (float)batch[gcl * 20];
        }
      }
    }
  }
}

extern "C" void kernel_launch(void* const* d_in, const int* in_sizes, int n_in,
                              void* d_out, int out_size, void* d_ws, size_t ws_size,
                              hipStream_t stream) {
  const float* x     = (const float*)d_in[0];
  const int*   batch = (const int*)d_in[2];
  const float* pw1 = (const float*)d_in[3];
  const float* pb1 = (const float*)d_in[4];
  const float* pg  = (const float*)d_in[5];
  const float* pbe = (const float*)d_in[6];
  const float* pw2 = (const float*)d_in[7];
  const float* pb2 = (const float*)d_in[8];
  const float* w1a = (const float*)d_in[9];
  const float* b1a = (const float*)d_in[10];
  const float* ga  = (const float*)d_in[11];
  const float* bea = (const float*)d_in[12];
  const float* w2a = (const float*)d_in[13];
  const float* b2a = (const float*)d_in[14];
  const float* w1b = (const float*)d_in[15];
  const float* b1b = (const float*)d_in[16];
  const float* gb  = (const float*)d_in[17];
  const float* beb = (const float*)d_in[18];
  const float* w2b = (const float*)d_in[19];
  const float* b2b = (const float*)d_in[20];
  const float* w1c = (const float*)d_in[21];
  const float* b1c = (const float*)d_in[22];
  const float* gc  = (const float*)d_in[23];
  const float* bec = (const float*)d_in[24];
  const float* w2c = (const float*)d_in[25];
  const float* b2c = (const float*)d_in[26];
  const float* ow1 = (const float*)d_in[27];
  const float* ob1 = (const float*)d_in[28];
  const float* og  = (const float*)d_in[29];
  const float* obe = (const float*)d_in[30];
  const float* ow2 = (const float*)d_in[31];
  const float* ob2 = (const float*)d_in[32];

  const int N = in_sizes[0] / 16;
  const int C = N / 20;
  short* ws16 = (short*)d_ws;
  float* out = (float*)d_out;

  hipLaunchKernelGGL(kT, dim3(10), dim3(256), 0, stream,
                     pw1, pw2, w1a, w2a, w1b, w2b, w1c, w2c, ow1, ow2, ws16);

  const int blocks = (C + 15) / 16;   // 16 clusters per block (4 waves x 4)
  hipLaunchKernelGGL(kF, dim3(blocks), dim3(256), 0, stream,
                     x, batch, (const short*)ws16,
                     pb1, pg, pbe, pb2,
                     b1a, ga, bea, b2a,
                     b1b, gb, beb, b2b,
                     b1c, gc, bec, b2c,
                     ob1, og, obe, ob2,
                     out, C);
}

// Round 7
// 308.059 us; speedup vs baseline: 5.4276x; 1.0539x over previous
//
#include <hip/hip_runtime.h>

// ---------------------------------------------------------------------------
// Barrier-free wave-autonomous design, TRANSPOSED MFMA epilogue.
// kT pre-transposes weights into d_ws as bf16 [f][k] (B-fragment layout).
// kF: wave owns 4 clusters = 80 nodes = 5 tiles; act LDS [node][feature] bf16.
// Matmul computed as D[feat][node] = W^T x X^T: A-operand = weight frags
// (same loads as before), B-operand = act rows (same loads as before), but
// C/D now has features in-lane: row(=feature)=quad*4+reg, col(=node)=lane&15.
// -> LN in-lane + 2 shfl_xor; LDS writes are short4 (ds_write_b64);
// bias/gamma/beta are per-lane float4 loads. ZERO __syncthreads.
// ---------------------------------------------------------------------------

#define ASTR 72   // act row stride in shorts

typedef short v8s __attribute__((ext_vector_type(8)));
typedef float v4f __attribute__((ext_vector_type(4)));

#define MFMA __builtin_amdgcn_mfma_f32_16x16x32_bf16

// ws layout (offsets in shorts)
#define OFF_PW1 0                        // 64 x 32 (K=16 zero-padded to 32)
#define OFF_PW2 2048                     // 64 x 64
#define OFF_LW1(L) (6144 + (L) * 6144)   // 64 x 64
#define OFF_LW2(L) (OFF_LW1(L) + 4096)   // 32 x 64
#define OFF_OW1 24576                    // 64 x 64
#define OFF_OW2 28672                    // 128 x 64

__device__ __forceinline__ short bfb(float v) {
  __bf16 b = (__bf16)v;
  return __builtin_bit_cast(short, b);
}

// ---- kT: transpose weights into bf16 B-fragment layout in ws ----
__global__ void kT(const float* __restrict__ pw1, const float* __restrict__ pw2,
                   const float* __restrict__ w1a, const float* __restrict__ w2a,
                   const float* __restrict__ w1b, const float* __restrict__ w2b,
                   const float* __restrict__ w1c, const float* __restrict__ w2c,
                   const float* __restrict__ ow1, const float* __restrict__ ow2,
                   short* __restrict__ ws) {
  const float* W; int K, F, Kpad, off;
  switch (blockIdx.x) {
    case 0: W = pw1; K = 16; F = 64;  Kpad = 32; off = OFF_PW1; break;
    case 1: W = pw2; K = 64; F = 64;  Kpad = 64; off = OFF_PW2; break;
    case 2: W = w1a; K = 64; F = 64;  Kpad = 64; off = OFF_LW1(0); break;
    case 3: W = w2a; K = 64; F = 32;  Kpad = 64; off = OFF_LW2(0); break;
    case 4: W = w1b; K = 64; F = 64;  Kpad = 64; off = OFF_LW1(1); break;
    case 5: W = w2b; K = 64; F = 32;  Kpad = 64; off = OFF_LW2(1); break;
    case 6: W = w1c; K = 64; F = 64;  Kpad = 64; off = OFF_LW1(2); break;
    case 7: W = w2c; K = 64; F = 32;  Kpad = 64; off = OFF_LW2(2); break;
    case 8: W = ow1; K = 64; F = 64;  Kpad = 64; off = OFF_OW1; break;
    default: W = ow2; K = 64; F = 128; Kpad = 64; off = OFF_OW2; break;
  }
  const int total = F * (Kpad >> 3);
  for (int i = threadIdx.x; i < total; i += blockDim.x) {
    const int f = i % F;
    const int kq = i / F;
    v8s h;
#pragma unroll
    for (int j = 0; j < 8; ++j) {
      const int k = kq * 8 + j;
      h[j] = bfb((k < K) ? W[k * F + f] : 0.f);
    }
    *(v8s*)(ws + off + f * Kpad + kq * 8) = h;
  }
}

// Transposed matmul over one 16-node tile: acc[t] covers features t*16..+15.
// Wf = NT*KS A-fragments (weights, regs); B-frag = act row reads (b128).
template <int NT, int KS>
__device__ __forceinline__ void mmT(const short* A, int tb, const v8s* Wf,
                                    const v4f* bias4, int col, int quad,
                                    v4f* acc) {
#pragma unroll
  for (int t = 0; t < NT; ++t) acc[t] = bias4[t];
#pragma unroll
  for (int ks = 0; ks < KS; ++ks) {
    const v8s b = *(const v8s*)(A + (tb + col) * ASTR + ks * 32 + quad * 8);
#pragma unroll
    for (int t = 0; t < NT; ++t)
      acc[t] = MFMA(Wf[t * KS + ks], b, acc[t], 0, 0, 0);
  }
}

// LayerNorm(64)+ReLU, features in-lane; short4 (b64) writes.
__device__ __forceinline__ void lnT_write(short* Aw, int tb, int col, int quad,
                                          v4f* acc, const v4f* g4,
                                          const v4f* be4) {
  float mu = 0.f, sq = 0.f;
#pragma unroll
  for (int t = 0; t < 4; ++t)
#pragma unroll
    for (int r = 0; r < 4; ++r) {
      mu += acc[t][r];
      sq = fmaf(acc[t][r], acc[t][r], sq);
    }
  mu += __shfl_xor(mu, 16); mu += __shfl_xor(mu, 32);
  sq += __shfl_xor(sq, 16); sq += __shfl_xor(sq, 32);
  mu *= (1.0f / 64.0f);
  const float var = sq * (1.0f / 64.0f) - mu * mu;
  const float rs = rsqrtf(var + 1e-5f);
#pragma unroll
  for (int t = 0; t < 4; ++t) {
    short4 s;
#pragma unroll
    for (int r = 0; r < 4; ++r) {
      float v = fmaf((acc[t][r] - mu) * rs, g4[t][r], be4[t][r]);
      ((short*)&s)[r] = bfb(fmaxf(v, 0.f));
    }
    *(short4*)(Aw + (tb + col) * ASTR + t * 16 + quad * 4) = s;
  }
}

template <int NT>
__device__ __forceinline__ void plainT_write(short* Aw, int tb, int col,
                                             int quad, v4f* acc) {
#pragma unroll
  for (int t = 0; t < NT; ++t) {
    short4 s;
#pragma unroll
    for (int r = 0; r < 4; ++r) ((short*)&s)[r] = bfb(acc[t][r]);
    *(short4*)(Aw + (tb + col) * ASTR + t * 16 + quad * 4) = s;
  }
}

// ---- kF: the whole network, one wave = 4 clusters, zero barriers ----
__global__ void __launch_bounds__(256, 3)
kF(const float* __restrict__ x, const int* __restrict__ batch,
   const short* __restrict__ wsW,
   const float* __restrict__ pb1, const float* __restrict__ pg,
   const float* __restrict__ pbe, const float* __restrict__ pb2,
   const float* __restrict__ b1a, const float* __restrict__ ga,
   const float* __restrict__ bea, const float* __restrict__ b2a,
   const float* __restrict__ b1b, const float* __restrict__ gb,
   const float* __restrict__ beb, const float* __restrict__ b2b,
   const float* __restrict__ b1c, const float* __restrict__ gc_,
   const float* __restrict__ bec, const float* __restrict__ b2c,
   const float* __restrict__ ob1, const float* __restrict__ og,
   const float* __restrict__ obe, const float* __restrict__ ob2,
   float* __restrict__ out, int C) {
  __shared__ __align__(16) short act[4 * 80 * ASTR];
  const int tid = threadIdx.x;
  const int lane = tid & 63;
  const int wave = tid >> 6;
  const int col = lane & 15;
  const int quad = lane >> 4;
  const int cbase = blockIdx.x * 16 + wave * 4;
  if (cbase >= C) return;
  const int nc = min(4, C - cbase);
  const int nrows = nc * 20;
  const int ntiles = (nrows + 15) >> 4;
  short* A = act + wave * 80 * ASTR;

  // ---- load x -> bf16 cols 0..15, zero cols 16..31 ----
  {
    const float4* x4 = (const float4*)x;
    const long nb = (long)cbase * 20;
    const short4 z = {0, 0, 0, 0};
    for (int i = lane; i < nrows * 4; i += 64) {
      const int row = i >> 2, e = i & 3;
      float4 v = x4[(nb + row) * 4 + e];
      short4 s = {bfb(v.x), bfb(v.y), bfb(v.z), bfb(v.w)};
      *(short4*)(A + row * ASTR + e * 4) = s;
      *(short4*)(A + row * ASTR + 16 + e * 4) = z;
    }
    if (nrows < ntiles * 16) {
      for (int i = lane; i < (ntiles * 16 - nrows) * 18; i += 64) {
        const int row = nrows + i / 18, e = i % 18;
        *(short4*)(A + row * ASTR + e * 4) = z;
      }
    }
  }

  // ---- pre-MLP stage 1: 16(pad32) -> 64, LN, ReLU ----
  {
    v8s Wf[4]; v4f b4[4], g4[4], be4[4];
#pragma unroll
    for (int t = 0; t < 4; ++t) {
      Wf[t] = *(const v8s*)(wsW + OFF_PW1 + (t * 16 + col) * 32 + quad * 8);
      b4[t]  = *(const v4f*)(pb1 + t * 16 + quad * 4);
      g4[t]  = *(const v4f*)(pg  + t * 16 + quad * 4);
      be4[t] = *(const v4f*)(pbe + t * 16 + quad * 4);
    }
    for (int T = 0; T < ntiles; ++T) {
      v4f acc[4];
      mmT<4, 1>(A, T * 16, Wf, b4, col, quad, acc);
      lnT_write(A, T * 16, col, quad, acc, g4, be4);
    }
  }

  // ---- pre-MLP stage 2: 64 -> 64 (no LN) ----
  {
    v8s Wf[8]; v4f b4[4];
#pragma unroll
    for (int t = 0; t < 4; ++t) {
#pragma unroll
      for (int ks = 0; ks < 2; ++ks)
        Wf[t * 2 + ks] = *(const v8s*)(wsW + OFF_PW2 + (t * 16 + col) * 64 + ks * 32 + quad * 8);
      b4[t] = *(const v4f*)(pb2 + t * 16 + quad * 4);
    }
    for (int T = 0; T < ntiles; ++T) {
      v4f acc[4];
      mmT<4, 2>(A, T * 16, Wf, b4, col, quad, acc);
      plainT_write<4>(A, T * 16, col, quad, acc);
    }
  }

  // ---- 3 subgraph layers ----
  const float* B1p[3] = {b1a, b1b, b1c};
  const float* Gp[3]  = {ga, gb, gc_};
  const float* BEp[3] = {bea, beb, bec};
  const float* B2p[3] = {b2a, b2b, b2c};

  for (int L = 0; L < 3; ++L) {
    v8s W1f[8], W2f[4];
    v4f b14[4], g4[4], be4[4], b24[2];
    const short* w1 = wsW + OFF_LW1(L);
    const short* w2 = wsW + OFF_LW2(L);
#pragma unroll
    for (int t = 0; t < 4; ++t) {
#pragma unroll
      for (int ks = 0; ks < 2; ++ks)
        W1f[t * 2 + ks] = *(const v8s*)(w1 + (t * 16 + col) * 64 + ks * 32 + quad * 8);
      b14[t] = *(const v4f*)(B1p[L] + t * 16 + quad * 4);
      g4[t]  = *(const v4f*)(Gp[L]  + t * 16 + quad * 4);
      be4[t] = *(const v4f*)(BEp[L] + t * 16 + quad * 4);
    }
#pragma unroll
    for (int t = 0; t < 2; ++t) {
#pragma unroll
      for (int ks = 0; ks < 2; ++ks)
        W2f[t * 2 + ks] = *(const v8s*)(w2 + (t * 16 + col) * 64 + ks * 32 + quad * 8);
      b24[t] = *(const v4f*)(B2p[L] + t * 16 + quad * 4);
    }
    for (int T = 0; T < ntiles; ++T) {
      v4f acc[4];
      mmT<4, 2>(A, T * 16, W1f, b14, col, quad, acc);
      lnT_write(A, T * 16, col, quad, acc, g4, be4);
      v4f h[2];
      mmT<2, 2>(A, T * 16, W2f, b24, col, quad, h);
      plainT_write<2>(A, T * 16, col, quad, h);
    }
    // ---- intra-wave pooling: 4 clusters x 16 uint-cols ----
    {
      const int cl = quad, jp = col;
      if (cl < nc) {
        const uint* AU = (const uint*)A;
        float m0 = -3.4e38f, m1 = -3.4e38f;
#pragma unroll
        for (int r = 0; r < 20; ++r) {
          const uint v = AU[(cl * 20 + r) * (ASTR / 2) + jp];
          m0 = fmaxf(m0, __builtin_bit_cast(float, v << 16));
          m1 = fmaxf(m1, __builtin_bit_cast(float, v & 0xFFFF0000u));
        }
        const uint pv = (uint)(unsigned short)bfb(m0) |
                        ((uint)(unsigned short)bfb(m1) << 16);
        uint* AW = (uint*)A;
        if (L < 2) {
#pragma unroll
          for (int r = 0; r < 20; ++r)
            AW[(cl * 20 + r) * (ASTR / 2) + 16 + jp] = pv;
        } else {
          // segmax(concat[h,pooled]) == [pooled,pooled] -> rows 0..3 = pooled
          AW[cl * (ASTR / 2) + jp] = pv;
          AW[cl * (ASTR / 2) + 16 + jp] = pv;
        }
      }
    }
  }

  // ---- fused output MLP on rows 0..15 (rows 0..nc-1 valid) ----
  {
    v8s Wf[8]; v4f b4[4], g4[4], be4[4];
#pragma unroll
    for (int t = 0; t < 4; ++t) {
#pragma unroll
      for (int ks = 0; ks < 2; ++ks)
        Wf[t * 2 + ks] = *(const v8s*)(wsW + OFF_OW1 + (t * 16 + col) * 64 + ks * 32 + quad * 8);
      b4[t]  = *(const v4f*)(ob1 + t * 16 + quad * 4);
      g4[t]  = *(const v4f*)(og  + t * 16 + quad * 4);
      be4[t] = *(const v4f*)(obe + t * 16 + quad * 4);
    }
    v4f acc[4];
    mmT<4, 2>(A, 0, Wf, b4, col, quad, acc);
    lnT_write(A, 0, col, quad, acc, g4, be4);
  }
  {
    v4f acc[8];
    const v8s bb0 = *(const v8s*)(A + col * ASTR + quad * 8);
    const v8s bb1 = *(const v8s*)(A + col * ASTR + 32 + quad * 8);
#pragma unroll
    for (int half = 0; half < 2; ++half) {
      v8s Wf[8];
#pragma unroll
      for (int t = 0; t < 4; ++t)
#pragma unroll
        for (int ks = 0; ks < 2; ++ks)
          Wf[t * 2 + ks] = *(const v8s*)(wsW + OFF_OW2 +
                             ((half * 4 + t) * 16 + col) * 64 + ks * 32 + quad * 8);
#pragma unroll
      for (int t = 0; t < 4; ++t) {
        v4f a = *(const v4f*)(ob2 + (half * 4 + t) * 16 + quad * 4);
        a = MFMA(Wf[t * 2], bb0, a, 0, 0, 0);
        a = MFMA(Wf[t * 2 + 1], bb1, a, 0, 0, 0);
        acc[half * 4 + t] = a;
      }
    }
    // L2 norm over 128 feats (32 in-lane + cross-quad)
    float sq = 0.f;
#pragma unroll
    for (int t = 0; t < 8; ++t)
#pragma unroll
      for (int r = 0; r < 4; ++r) sq = fmaf(acc[t][r], acc[t][r], sq);
    sq += __shfl_xor(sq, 16); sq += __shfl_xor(sq, 32);
    const float inv = 1.0f / fmaxf(sqrtf(sq), 1e-12f);
    if (col < nc) {
      const long gcl = cbase + col;
#pragma unroll
      for (int t = 0; t < 8; ++t) {
        float4 v = {acc[t][0] * inv, acc[t][1] * inv,
                    acc[t][2] * inv, acc[t][3] * inv};
        *(float4*)(out + gcl * 128 + t * 16 + quad * 4) = v;
      }
      if (quad == 0) out[(long)C * 128 + gcl] = (float)batch[gcl * 20];
    }
  }
}

extern "C" void kernel_launch(void* const* d_in, const int* in_sizes, int n_in,
                              void* d_out, int out_size, void* d_ws, size_t ws_size,
                              hipStream_t stream) {
  const float* x     = (const float*)d_in[0];
  const int*   batch = (const int*)d_in[2];
  const float* pw1 = (const float*)d_in[3];
  const float* pb1 = (const float*)d_in[4];
  const float* pg  = (const float*)d_in[5];
  const float* pbe = (const float*)d_in[6];
  const float* pw2 = (const float*)d_in[7];
  const float* pb2 = (const float*)d_in[8];
  const float* w1a = (const float*)d_in[9];
  const float* b1a = (const float*)d_in[10];
  const float* ga  = (const float*)d_in[11];
  const float* bea = (const float*)d_in[12];
  const float* w2a = (const float*)d_in[13];
  const float* b2a = (const float*)d_in[14];
  const float* w1b = (const float*)d_in[15];
  const float* b1b = (const float*)d_in[16];
  const float* gb  = (const float*)d_in[17];
  const float* beb = (const float*)d_in[18];
  const float* w2b = (const float*)d_in[19];
  const float* b2b = (const float*)d_in[20];
  const float* w1c = (const float*)d_in[21];
  const float* b1c = (const float*)d_in[22];
  const float* gc  = (const float*)d_in[23];
  const float* bec = (const float*)d_in[24];
  const float* w2c = (const float*)d_in[25];
  const float* b2c = (const float*)d_in[26];
  const float* ow1 = (const float*)d_in[27];
  const float* ob1 = (const float*)d_in[28];
  const float* og  = (const float*)d_in[29];
  const float* obe = (const float*)d_in[30];
  const float* ow2 = (const float*)d_in[31];
  const float* ob2 = (const float*)d_in[32];

  const int N = in_sizes[0] / 16;
  const int C = N / 20;
  short* ws16 = (short*)d_ws;
  float* out = (float*)d_out;

  hipLaunchKernelGGL(kT, dim3(10), dim3(256), 0, stream,
                     pw1, pw2, w1a, w2a, w1b, w2b, w1c, w2c, ow1, ow2, ws16);

  const int blocks = (C + 15) / 16;   // 16 clusters per block (4 waves x 4)
  hipLaunchKernelGGL(kF, dim3(blocks), dim3(256), 0, stream,
                     x, batch, (const short*)ws16,
                     pb1, pg, pbe, pb2,
                     b1a, ga, bea, b2a,
                     b1b, gb, beb, b2b,
                     b1c, gc, bec, b2c,
                     ob1, og, obe, ob2,
                     out, C);
}